// Round 1
// baseline (699.190 us; speedup 1.0000x reference)
//
#include <hip/hip_runtime.h>
#include <hip/hip_bf16.h>

#define D 256
#define NH 8
#define DH 32
#define NL 4
#define NP 4
#define DFFN 1024
#define LEN_IN 21760
#define NB 8
#define LQ 1000

typedef __hip_bfloat16 bf16;
typedef __attribute__((ext_vector_type(8))) short s8v;
typedef __attribute__((ext_vector_type(4))) float f4v;

template <typename T> __device__ inline T fromF(float x);
template <> __device__ inline float fromF<float>(float x) { return x; }
template <> __device__ inline bf16 fromF<bf16>(float x) { return __float2bfloat16(x); }

// fp32 -> bf16 round-to-nearest-even, branchless (finite inputs)
__device__ inline short bfr(float f) {
    unsigned u = __float_as_uint(f);
    u += 0x7fff + ((u >> 16) & 1);
    return (short)(u >> 16);
}
__device__ inline s8v pack8(float4 x, float4 y) {
    s8v r;
    r[0] = bfr(x.x); r[1] = bfr(x.y); r[2] = bfr(x.z); r[3] = bfr(x.w);
    r[4] = bfr(y.x); r[5] = bfr(y.y); r[6] = bfr(y.z); r[7] = bfr(y.w);
    return r;
}

// hardware packed fp32->bf16 (RNE), 2 elems / instruction
__device__ inline unsigned cvtpk(float a, float b) {
    unsigned r;
    asm("v_cvt_pk_bf16_f32 %0, %1, %2" : "=v"(r) : "v"(a), "v"(b));
    return r;
}
__device__ inline s8v pkcvt8(float4 a, float4 b) {
    union { s8v v; unsigned u[4]; } r;
    r.u[0] = cvtpk(a.x, a.y);
    r.u[1] = cvtpk(a.z, a.w);
    r.u[2] = cvtpk(b.x, b.y);
    r.u[3] = cvtpk(b.z, b.w);
    return r.v;
}

// ---------------- weight pre-pack: all 8 fp32 weight mats -> one bf16 buffer ----
// float4-granular. Segment sizes (float4 units):
// sa_in 49152 | sa_out 16384 | off 16384 | aw 8192 | val 16384 | outp 16384 | ffn1 65536 | ffn2 65536
// total 253952 float4 = 992 blocks * 256 threads
__global__ __launch_bounds__(256) void pack_weights(const float* __restrict__ s0, const float* __restrict__ s1,
                                                    const float* __restrict__ s2, const float* __restrict__ s3,
                                                    const float* __restrict__ s4, const float* __restrict__ s5,
                                                    const float* __restrict__ s6, const float* __restrict__ s7,
                                                    bf16* __restrict__ dst) {
    int g = blockIdx.x * 256 + threadIdx.x;
    const float* s; int base;
    if      (g <  49152) { s = s0; base = 0;      }
    else if (g <  65536) { s = s1; base = 49152;  }
    else if (g <  81920) { s = s2; base = 65536;  }
    else if (g <  90112) { s = s3; base = 81920;  }
    else if (g < 106496) { s = s4; base = 90112;  }
    else if (g < 122880) { s = s5; base = 106496; }
    else if (g < 188416) { s = s6; base = 122880; }
    else                 { s = s7; base = 188416; }
    float4 v = ((const float4*)s)[g - base];
    short4 o; o.x = bfr(v.x); o.y = bfr(v.y); o.z = bfr(v.z); o.w = bfr(v.w);
    ((short4*)dst)[g] = o;
}

// ---------------- direct-from-global MFMA GEMM ----------------
// C[M,N] = (A(+A2))[M,K] @ W[N,K]^T + bias, optional relu.
// No LDS, no barriers: each lane loads its MFMA fragments straight from
// global (A fp32 -> v_cvt_pk_bf16_f32 in-register; W pre-packed bf16,
// L2-resident). Block = (MT*32) rows x 128 cols, 4 waves (2m x 2n),
// per-wave tile = MT*16 x 64, acc[MT][4]. M % (MT*32) == 0, N % 128 == 0,
// K % 32 == 0 guaranteed by caller.
template <typename TA, typename TC, int MT, bool ADD2>
__global__ __launch_bounds__(256) void gemm_direct(const TA* __restrict__ A, const float* __restrict__ A2,
                                                   const bf16* __restrict__ W, const float* __restrict__ bias,
                                                   TC* __restrict__ C, int M, int N, int K, int do_relu) {
    const int tid = threadIdx.x;
    const int lane = tid & 63, wave = tid >> 6;
    const int fr = lane & 15, fq = lane >> 4;
    const int n0 = blockIdx.x * 128;
    const int wrow = blockIdx.y * (MT * 32) + (wave >> 1) * (MT * 16);
    const int wn = n0 + (wave & 1) * 64;
    (void)M;

    const TA* ap[MT];
    const float* a2p[MT];
#pragma unroll
    for (int i = 0; i < MT; ++i) {
        size_t r = (size_t)(wrow + i * 16 + fr);
        ap[i] = A + r * K + fq * 8;
        if constexpr (ADD2) a2p[i] = A2 + r * K + fq * 8;
    }
    const bf16* wp[4];
#pragma unroll
    for (int j = 0; j < 4; ++j) wp[j] = W + (size_t)(wn + j * 16 + fr) * K + fq * 8;

    f4v acc[MT][4];
#pragma unroll
    for (int i = 0; i < MT; ++i)
#pragma unroll
        for (int j = 0; j < 4; ++j) acc[i][j] = (f4v){0.f, 0.f, 0.f, 0.f};

    for (int k0 = 0; k0 < K; k0 += 32) {
        s8v bfv[4];
#pragma unroll
        for (int j = 0; j < 4; ++j) { bfv[j] = *(const s8v*)wp[j]; wp[j] += 32; }
        s8v af[MT];
#pragma unroll
        for (int i = 0; i < MT; ++i) {
            if constexpr (sizeof(TA) == 2) {
                af[i] = *(const s8v*)ap[i];
            } else {
                float4 x0 = *(const float4*)ap[i];
                float4 x1 = *(const float4*)(ap[i] + 4);
                if constexpr (ADD2) {
                    float4 y0 = *(const float4*)a2p[i];
                    float4 y1 = *(const float4*)(a2p[i] + 4);
                    x0.x += y0.x; x0.y += y0.y; x0.z += y0.z; x0.w += y0.w;
                    x1.x += y1.x; x1.y += y1.y; x1.z += y1.z; x1.w += y1.w;
                    a2p[i] += 32;
                }
                af[i] = pkcvt8(x0, x1);
            }
            ap[i] += 32;
        }
#pragma unroll
        for (int i = 0; i < MT; ++i)
#pragma unroll
            for (int j = 0; j < 4; ++j)
                acc[i][j] = __builtin_amdgcn_mfma_f32_16x16x32_bf16(af[i], bfv[j], acc[i][j], 0, 0, 0);
    }

#pragma unroll
    for (int j = 0; j < 4; ++j) {
        const int col = wn + j * 16 + fr;
        const float bb = bias[col];
#pragma unroll
        for (int i = 0; i < MT; ++i) {
            const int rbase = wrow + i * 16 + fq * 4;
#pragma unroll
            for (int r = 0; r < 4; ++r) {
                float v = acc[i][j][r] + bb;
                if (do_relu) v = fmaxf(v, 0.f);
                C[(size_t)(rbase + r) * N + col] = fromF<TC>(v);
            }
        }
    }
}

// ---------------- MFMA flash self-attention ----------------
__global__ __launch_bounds__(256) void attn_mfma(const float* __restrict__ q, const float* __restrict__ k,
                                                 const float* __restrict__ v, float* __restrict__ out) {
    const int h = blockIdx.y, n = blockIdx.z;
    const int tid = threadIdx.x, wave = tid >> 6, lane = tid & 63;
    const int fr = lane & 15, fq = lane >> 4;
    __shared__ short Ks[32 * 40];
    __shared__ short Vt[32 * 40];
    __shared__ short Pl[4][16 * 40];
    const int q0 = blockIdx.x * 64 + wave * 16;

    s8v qfrag;
    {
        int qr = q0 + fr; if (qr >= LQ) qr = LQ - 1;
        const float* qp = q + ((size_t)(n * LQ + qr)) * D + h * DH + fq * 8;
        float4 t0 = *(const float4*)qp;
        float4 t1 = *(const float4*)(qp + 4);
        const float sc = 0.17677669529663687f;
        t0.x *= sc; t0.y *= sc; t0.z *= sc; t0.w *= sc;
        t1.x *= sc; t1.y *= sc; t1.z *= sc; t1.w *= sc;
        qfrag = pack8(t0, t1);
    }

    f4v O0 = {0.f, 0.f, 0.f, 0.f}, O1 = {0.f, 0.f, 0.f, 0.f};
    float mrow[4] = {-1e30f, -1e30f, -1e30f, -1e30f};
    float lrow[4] = {0.f, 0.f, 0.f, 0.f};

    for (int kt = 0; kt < LQ; kt += 32) {
        __syncthreads();
        {
            int key = tid >> 3, d4 = (tid & 7) * 4;
            int gk = kt + key; if (gk >= LQ) gk = LQ - 1;
            const float* kp = k + ((size_t)(n * LQ + gk)) * D + h * DH + d4;
            float4 t = *(const float4*)kp;
            short4 pk; pk.x = bfr(t.x); pk.y = bfr(t.y); pk.z = bfr(t.z); pk.w = bfr(t.w);
            *(short4*)&Ks[key * 40 + d4] = pk;
        }
        {
            int d = tid & 31, key0 = (tid >> 5) * 4;
            float vv[4];
#pragma unroll
            for (int i = 0; i < 4; ++i) {
                int gk = kt + key0 + i; if (gk >= LQ) gk = LQ - 1;
                vv[i] = v[((size_t)(n * LQ + gk)) * D + h * DH + d];
            }
            short4 pk; pk.x = bfr(vv[0]); pk.y = bfr(vv[1]); pk.z = bfr(vv[2]); pk.w = bfr(vv[3]);
            *(short4*)&Vt[d * 40 + key0] = pk;
        }
        __syncthreads();

        f4v s0 = {0.f, 0.f, 0.f, 0.f}, s1 = {0.f, 0.f, 0.f, 0.f};
        s8v kf0 = *(s8v*)&Ks[fr * 40 + fq * 8];
        s8v kf1 = *(s8v*)&Ks[(16 + fr) * 40 + fq * 8];
        s0 = __builtin_amdgcn_mfma_f32_16x16x32_bf16(qfrag, kf0, s0, 0, 0, 0);
        s1 = __builtin_amdgcn_mfma_f32_16x16x32_bf16(qfrag, kf1, s1, 0, 0, 0);
        const bool val0 = (kt + fr) < LQ, val1 = (kt + 16 + fr) < LQ;

        float p0[4], p1[4], alpha[4];
#pragma unroll
        for (int r = 0; r < 4; ++r) {
            float a = val0 ? s0[r] : -1e30f;
            float b = val1 ? s1[r] : -1e30f;
            float mx = fmaxf(a, b);
            mx = fmaxf(mx, __shfl_xor(mx, 1, 64));
            mx = fmaxf(mx, __shfl_xor(mx, 2, 64));
            mx = fmaxf(mx, __shfl_xor(mx, 4, 64));
            mx = fmaxf(mx, __shfl_xor(mx, 8, 64));
            float mnew = fmaxf(mrow[r], mx);
            float al = __expf(mrow[r] - mnew);
            float e0 = __expf(a - mnew);
            float e1 = __expf(b - mnew);
            float ps = e0 + e1;
            ps += __shfl_xor(ps, 1, 64);
            ps += __shfl_xor(ps, 2, 64);
            ps += __shfl_xor(ps, 4, 64);
            ps += __shfl_xor(ps, 8, 64);
            lrow[r] = lrow[r] * al + ps;
            mrow[r] = mnew;
            alpha[r] = al;
            p0[r] = e0; p1[r] = e1;
        }

        short* pw = Pl[wave];
#pragma unroll
        for (int r = 0; r < 4; ++r) {
            pw[(fq * 4 + r) * 40 + fr] = bfr(p0[r]);
            pw[(fq * 4 + r) * 40 + 16 + fr] = bfr(p1[r]);
        }
        __builtin_amdgcn_s_waitcnt(0);
        s8v pfrag = *(s8v*)&pw[fr * 40 + fq * 8];
        s8v vf0 = *(s8v*)&Vt[fr * 40 + fq * 8];
        s8v vf1 = *(s8v*)&Vt[(16 + fr) * 40 + fq * 8];
#pragma unroll
        for (int r = 0; r < 4; ++r) { O0[r] *= alpha[r]; O1[r] *= alpha[r]; }
        O0 = __builtin_amdgcn_mfma_f32_16x16x32_bf16(pfrag, vf0, O0, 0, 0, 0);
        O1 = __builtin_amdgcn_mfma_f32_16x16x32_bf16(pfrag, vf1, O1, 0, 0, 0);
    }

#pragma unroll
    for (int r = 0; r < 4; ++r) {
        int qrow = q0 + fq * 4 + r;
        if (qrow < LQ) {
            float inv = 1.0f / lrow[r];
            float* op = out + ((size_t)(n * LQ + qrow)) * D + h * DH;
            op[fr] = O0[r] * inv;
            op[16 + fr] = O1[r] * inv;
        }
    }
}

// ---------------- residual + layernorm ----------------
__global__ __launch_bounds__(256) void ln_res_kernel(const float* __restrict__ base, const float* __restrict__ delta,
                                                     const float* __restrict__ g, const float* __restrict__ b,
                                                     float* __restrict__ out) {
    __shared__ float scratch[8];
    const size_t row = blockIdx.x;
    const int d = threadIdx.x;
    float x = base[row * D + d] + delta[row * D + d];
    float s1 = x, s2 = x * x;
    for (int o = 32; o > 0; o >>= 1) {
        s1 += __shfl_down(s1, o, 64);
        s2 += __shfl_down(s2, o, 64);
    }
    const int w = threadIdx.x >> 6, lane = threadIdx.x & 63;
    if (lane == 0) { scratch[w] = s1; scratch[4 + w] = s2; }
    __syncthreads();
    s1 = scratch[0] + scratch[1] + scratch[2] + scratch[3];
    s2 = scratch[4] + scratch[5] + scratch[6] + scratch[7];
    float mean = s1 * (1.0f / 256.0f);
    float var = s2 * (1.0f / 256.0f) - mean * mean;
    float rstd = rsqrtf(var + 1e-5f);
    float y = (x - mean) * rstd * g[d] + b[d];
    out[row * D + d] = y;
}

// ---------------- softmax over 16 (NL*NP) ----------------
__global__ __launch_bounds__(256) void aw_softmax_kernel(float* __restrict__ aw, int ngrp) {
    int t = blockIdx.x * 256 + threadIdx.x;
    if (t >= ngrp) return;
    float* p = aw + (size_t)t * 16;
    float m = p[0];
#pragma unroll
    for (int i = 1; i < 16; ++i) m = fmaxf(m, p[i]);
    float s = 0.f;
    float e[16];
#pragma unroll
    for (int i = 0; i < 16; ++i) { e[i] = __expf(p[i] - m); s += e[i]; }
    float inv = 1.0f / s;
#pragma unroll
    for (int i = 0; i < 16; ++i) p[i] = e[i] * inv;
}

// ---------------- MS-deformable bilinear sampling ----------------
// block 256 = 4 waves, wave = 1 query. lane = l*16 + c: subgroup l owns level l
// (W/H/START loop-invariant), lane c owns channels {2c, 2c+1} via one dword load.
__global__ __launch_bounds__(256) void deform_kernel(const bf16* __restrict__ value, const float* __restrict__ offs,
                                                     const float* __restrict__ aw, const float* __restrict__ refp,
                                                     float* __restrict__ out) {
    const int h = blockIdx.y, n = blockIdx.z;
    const int tid = threadIdx.x;
    const int wave = tid >> 6, lane = tid & 63;
    const int qi = blockIdx.x * 4 + wave;
    const int c = lane & 15;          // channel pair -> channels 2c, 2c+1
    const int l = lane >> 4;          // level
    const size_t row = (size_t)n * LQ + qi;
    const int W = 128 >> l, H = 128 >> l;
    const int START[4] = {0, 16384, 20480, 21504};
    const float invW = 1.0f / W, invH = 1.0f / H;

    const float rx = refp[(row * NL + l) * 2 + 0];
    const float ry = refp[(row * NL + l) * 2 + 1];
    const bf16* vbase = value + ((size_t)n * LEN_IN + START[l]) * D + h * DH + 2 * c;
    const float* offp = offs + row * D + (h * NL + l) * NP * 2;
    const float* awp = aw + row * 128 + h * 16 + l * 4;

    float acc0 = 0.f, acc1 = 0.f;
#pragma unroll
    for (int p = 0; p < 4; ++p) {
        float ox = offp[p * 2 + 0];
        float oy = offp[p * 2 + 1];
        float wa = awp[p];
        float x = (rx + ox * invW) * W - 0.5f;
        float y = (ry + oy * invH) * H - 0.5f;
        float xf = floorf(x), yf = floorf(y);
        float lx = x - xf, ly = y - yf;
        int x0 = (int)xf, y0 = (int)yf;
        int x1 = x0 + 1, y1 = y0 + 1;
        float vx0 = (x0 >= 0 && x0 < W) ? 1.f : 0.f;
        float vx1 = (x1 >= 0 && x1 < W) ? 1.f : 0.f;
        float vy0 = (y0 >= 0 && y0 < H) ? 1.f : 0.f;
        float vy1 = (y1 >= 0 && y1 < H) ? 1.f : 0.f;
        int x0c = min(max(x0, 0), W - 1), x1c = min(max(x1, 0), W - 1);
        int y0c = min(max(y0, 0), H - 1), y1c = min(max(y1, 0), H - 1);
        float w00 = wa * (1.f - ly) * (1.f - lx) * vy0 * vx0;
        float w01 = wa * (1.f - ly) * lx * vy0 * vx1;
        float w10 = wa * ly * (1.f - lx) * vy1 * vx0;
        float w11 = wa * ly * lx * vy1 * vx1;
        unsigned u00 = *(const unsigned*)(vbase + (size_t)(y0c * W + x0c) * D);
        unsigned u01 = *(const unsigned*)(vbase + (size_t)(y0c * W + x1c) * D);
        unsigned u10 = *(const unsigned*)(vbase + (size_t)(y1c * W + x0c) * D);
        unsigned u11 = *(const unsigned*)(vbase + (size_t)(y1c * W + x1c) * D);
        acc0 += w00 * __uint_as_float(u00 << 16) + w01 * __uint_as_float(u01 << 16)
              + w10 * __uint_as_float(u10 << 16) + w11 * __uint_as_float(u11 << 16);
        acc1 += w00 * __uint_as_float(u00 & 0xffff0000u) + w01 * __uint_as_float(u01 & 0xffff0000u)
              + w10 * __uint_as_float(u10 & 0xffff0000u) + w11 * __uint_as_float(u11 & 0xffff0000u);
    }
    acc0 += __shfl_xor(acc0, 16, 64); acc0 += __shfl_xor(acc0, 32, 64);
    acc1 += __shfl_xor(acc1, 16, 64); acc1 += __shfl_xor(acc1, 32, 64);
    if (l == 0) {
        float2 st = {acc0, acc1};
        *(float2*)(out + row * D + h * DH + 2 * c) = st;
    }
}

// ---------------- host ----------------
extern "C" void kernel_launch(void* const* d_in, const int* in_sizes, int n_in,
                              void* d_out, int out_size, void* d_ws, size_t ws_size,
                              hipStream_t stream) {
    const float* tgt = (const float*)d_in[0];
    const float* qpos = (const float*)d_in[1];
    const float* refp = (const float*)d_in[2];
    const float* src = (const float*)d_in[3];
    const float* sa_in_w = (const float*)d_in[6];
    const float* sa_in_b = (const float*)d_in[7];
    const float* sa_out_w = (const float*)d_in[8];
    const float* sa_out_b = (const float*)d_in[9];
    const float* norm2_g = (const float*)d_in[10];
    const float* norm2_b = (const float*)d_in[11];
    const float* off_w = (const float*)d_in[12];
    const float* off_b = (const float*)d_in[13];
    const float* aw_w = (const float*)d_in[14];
    const float* aw_b = (const float*)d_in[15];
    const float* val_w = (const float*)d_in[16];
    const float* val_b = (const float*)d_in[17];
    const float* outp_w = (const float*)d_in[18];
    const float* outp_b = (const float*)d_in[19];
    const float* norm1_g = (const float*)d_in[20];
    const float* norm1_b = (const float*)d_in[21];
    const float* ffn_w1 = (const float*)d_in[22];
    const float* ffn_b1 = (const float*)d_in[23];
    const float* ffn_w2 = (const float*)d_in[24];
    const float* ffn_b2 = (const float*)d_in[25];
    const float* norm3_g = (const float*)d_in[26];
    const float* norm3_b = (const float*)d_in[27];
    float* outp = (float*)d_out;

    const size_t NTOK = (size_t)NB * LQ;          // 8000
    const size_t NE = NTOK * D;                   // 2,048,000
    float* w = (float*)d_ws;
    size_t off = 0;
    auto alloc = [&](size_t n) { float* p = w + off; off += n; return p; };
    float* bufA = alloc(NE);          // att -> dout
    float* bufB = alloc(NE);          // q -> sap -> ca
    float* bufC = alloc(NE);          // k -> ff
    float* bufD = alloc(NE);          // v -> offs
    float* tgt2 = alloc(NE);
    float* tgt3 = alloc(NE);
    float* awb = alloc(NTOK * 128);
    bf16* mid = (bf16*)alloc(NTOK * DFFN / 2);            // FFN mid, bf16
    bf16* value = (bf16*)alloc((size_t)NB * LEN_IN * D / 2); // (NB*LEN_IN, D) bf16
    bf16* wb = (bf16*)alloc(507904);                      // packed bf16 weights (1,015,808 elems)

    // packed weight layout (element offsets)
    const bf16* wq    = wb;            // sa_in rows 0..255
    const bf16* wk    = wb + 65536;    // sa_in rows 256..511
    const bf16* wv    = wb + 131072;   // sa_in rows 512..767
    const bf16* wo    = wb + 196608;   // sa_out
    const bf16* woff  = wb + 262144;
    const bf16* waw   = wb + 327680;
    const bf16* wval  = wb + 360448;
    const bf16* woutp = wb + 425984;
    const bf16* wf1   = wb + 491520;
    const bf16* wf2   = wb + 753664;

    const int M8K = (int)NTOK;        // 8000
    dim3 g8(2, M8K / 64);             // N=256 GEMMs, 64-row tiles -> 250 blocks
    dim3 g8aw(1, M8K / 64);           // N=128
    dim3 g8f1(DFFN / 128, M8K / 64);  // N=1024 -> 1000 blocks
    dim3 gVal(2, (NB * LEN_IN) / 128);// 174080 rows, 128-row tiles -> 2720 blocks

    pack_weights<<<992, 256, 0, stream>>>(sa_in_w, sa_out_w, off_w, aw_w, val_w, outp_w, ffn_w1, ffn_w2, wb);

    // ---- self attention ----
    gemm_direct<float, float, 2, true><<<g8, 256, 0, stream>>>(tgt, qpos, wq, sa_in_b, bufB, M8K, D, D, 0);        // Q
    gemm_direct<float, float, 2, true><<<g8, 256, 0, stream>>>(tgt, qpos, wk, sa_in_b + 256, bufC, M8K, D, D, 0);  // K
    gemm_direct<float, float, 2, false><<<g8, 256, 0, stream>>>(tgt, nullptr, wv, sa_in_b + 512, bufD, M8K, D, D, 0); // V
    attn_mfma<<<dim3((LQ + 63) / 64, NH, NB), 256, 0, stream>>>(bufB, bufC, bufD, bufA);                           // att
    gemm_direct<float, float, 2, false><<<g8, 256, 0, stream>>>(bufA, nullptr, wo, sa_out_b, bufB, M8K, D, D, 0);  // sap
    ln_res_kernel<<<NTOK, 256, 0, stream>>>(tgt, bufB, norm2_g, norm2_b, tgt2);

    // ---- deformable attention ----
    gemm_direct<float, bf16, 4, false><<<gVal, 256, 0, stream>>>(src, nullptr, wval, val_b, value,
                                                                 NB * LEN_IN, D, D, 0);                            // value
    gemm_direct<float, float, 2, true><<<g8, 256, 0, stream>>>(tgt2, qpos, woff, off_b, bufD, M8K, D, D, 0);       // offsets
    gemm_direct<float, float, 2, true><<<g8aw, 256, 0, stream>>>(tgt2, qpos, waw, aw_b, awb, M8K, 128, D, 0);      // aw
    aw_softmax_kernel<<<(int)(NTOK * NH + 255) / 256, 256, 0, stream>>>(awb, (int)(NTOK * NH));
    deform_kernel<<<dim3(LQ / 4, NH, NB), 256, 0, stream>>>(value, bufD, awb, refp, bufA);                         // dout
    gemm_direct<float, float, 2, false><<<g8, 256, 0, stream>>>(bufA, nullptr, woutp, outp_b, bufB, M8K, D, D, 0); // ca
    ln_res_kernel<<<NTOK, 256, 0, stream>>>(tgt2, bufB, norm1_g, norm1_b, tgt3);

    // ---- FFN ----
    gemm_direct<float, bf16, 2, false><<<g8f1, 256, 0, stream>>>(tgt3, nullptr, wf1, ffn_b1, mid, M8K, DFFN, D, 1);
    gemm_direct<bf16, float, 2, false><<<g8, 256, 0, stream>>>(mid, nullptr, wf2, ffn_b2, bufC, M8K, D, DFFN, 0);  // ff
    ln_res_kernel<<<NTOK, 256, 0, stream>>>(tgt3, bufC, norm3_g, norm3_b, outp);
}

// Round 2
// 652.091 us; speedup vs baseline: 1.0722x; 1.0722x over previous
//
#include <hip/hip_runtime.h>
#include <hip/hip_bf16.h>

#define D 256
#define NH 8
#define DH 32
#define NL 4
#define NP 4
#define DFFN 1024
#define LEN_IN 21760
#define NB 8
#define LQ 1000

typedef __hip_bfloat16 bf16;
typedef __attribute__((ext_vector_type(8))) short s8v;
typedef __attribute__((ext_vector_type(4))) float f4v;

template <typename T> __device__ inline T fromF(float x);
template <> __device__ inline float fromF<float>(float x) { return x; }
template <> __device__ inline bf16 fromF<bf16>(float x) { return __float2bfloat16(x); }

// fp32 -> bf16 round-to-nearest-even, branchless (finite inputs)
__device__ inline short bfr(float f) {
    unsigned u = __float_as_uint(f);
    u += 0x7fff + ((u >> 16) & 1);
    return (short)(u >> 16);
}
__device__ inline s8v pack8(float4 x, float4 y) {
    s8v r;
    r[0] = bfr(x.x); r[1] = bfr(x.y); r[2] = bfr(x.z); r[3] = bfr(x.w);
    r[4] = bfr(y.x); r[5] = bfr(y.y); r[6] = bfr(y.z); r[7] = bfr(y.w);
    return r;
}

// hardware packed fp32->bf16 (RNE), 2 elems / instruction
__device__ inline unsigned cvtpk(float a, float b) {
    unsigned r;
    asm("v_cvt_pk_bf16_f32 %0, %1, %2" : "=v"(r) : "v"(a), "v"(b));
    return r;
}
__device__ inline s8v pkcvt8(float4 a, float4 b) {
    union { s8v v; unsigned u[4]; } r;
    r.u[0] = cvtpk(a.x, a.y);
    r.u[1] = cvtpk(a.z, a.w);
    r.u[2] = cvtpk(b.x, b.y);
    r.u[3] = cvtpk(b.z, b.w);
    return r.v;
}

// async global->LDS, 16B per lane. LDS dest is wave-uniform base + lane*16;
// passing per-thread (base + tid*16) satisfies that since tid*16 is linear in lane.
__device__ __forceinline__ void gload_lds16(const void* gsrc, void* ldst) {
    __builtin_amdgcn_global_load_lds(
        (const __attribute__((address_space(1))) unsigned int*)gsrc,
        (__attribute__((address_space(3))) unsigned int*)ldst,
        16, 0, 0);
}

// ---------------- weight pre-pack: all 8 fp32 weight mats -> one bf16 buffer ----
__global__ __launch_bounds__(256) void pack_weights(const float* __restrict__ s0, const float* __restrict__ s1,
                                                    const float* __restrict__ s2, const float* __restrict__ s3,
                                                    const float* __restrict__ s4, const float* __restrict__ s5,
                                                    const float* __restrict__ s6, const float* __restrict__ s7,
                                                    bf16* __restrict__ dst) {
    int g = blockIdx.x * 256 + threadIdx.x;
    const float* s; int base;
    if      (g <  49152) { s = s0; base = 0;      }
    else if (g <  65536) { s = s1; base = 49152;  }
    else if (g <  81920) { s = s2; base = 65536;  }
    else if (g <  90112) { s = s3; base = 81920;  }
    else if (g < 106496) { s = s4; base = 90112;  }
    else if (g < 122880) { s = s5; base = 106496; }
    else if (g < 188416) { s = s6; base = 122880; }
    else                 { s = s7; base = 188416; }
    float4 v = ((const float4*)s)[g - base];
    short4 o; o.x = bfr(v.x); o.y = bfr(v.y); o.z = bfr(v.z); o.w = bfr(v.w);
    ((short4*)dst)[g] = o;
}

// ---------------- direct-from-global MFMA GEMM (cache-hot A) ----------------
// C[M,N] = (A(+A2))[M,K] @ W[N,K]^T + bias, optional relu.
// K is compile-time -> fully unrolled (or x4 for K=1024) so the compiler can
// hoist loads across iterations (MLP). Use only where A is L2/L3-resident.
template <typename TA, typename TC, int MT, bool ADD2, int KK>
__global__ __launch_bounds__(256) void gemm_direct(const TA* __restrict__ A, const float* __restrict__ A2,
                                                   const bf16* __restrict__ W, const float* __restrict__ bias,
                                                   TC* __restrict__ C, int N, int do_relu) {
    const int tid = threadIdx.x;
    const int lane = tid & 63, wave = tid >> 6;
    const int fr = lane & 15, fq = lane >> 4;
    const int n0 = blockIdx.x * 128;
    const int wrow = blockIdx.y * (MT * 32) + (wave >> 1) * (MT * 16);
    const int wn = n0 + (wave & 1) * 64;

    const TA* ap[MT];
    const float* a2p[MT];
#pragma unroll
    for (int i = 0; i < MT; ++i) {
        size_t r = (size_t)(wrow + i * 16 + fr);
        ap[i] = A + r * KK + fq * 8;
        if constexpr (ADD2) a2p[i] = A2 + r * KK + fq * 8;
    }
    const bf16* wp[4];
#pragma unroll
    for (int j = 0; j < 4; ++j) wp[j] = W + (size_t)(wn + j * 16 + fr) * KK + fq * 8;

    f4v acc[MT][4];
#pragma unroll
    for (int i = 0; i < MT; ++i)
#pragma unroll
        for (int j = 0; j < 4; ++j) acc[i][j] = (f4v){0.f, 0.f, 0.f, 0.f};

    auto step = [&](int k0) {
        s8v bfv[4];
#pragma unroll
        for (int j = 0; j < 4; ++j) bfv[j] = *(const s8v*)(wp[j] + k0);
        s8v af[MT];
#pragma unroll
        for (int i = 0; i < MT; ++i) {
            if constexpr (sizeof(TA) == 2) {
                af[i] = *(const s8v*)((const bf16*)ap[i] + k0);
            } else {
                float4 x0 = *(const float4*)((const float*)ap[i] + k0);
                float4 x1 = *(const float4*)((const float*)ap[i] + k0 + 4);
                if constexpr (ADD2) {
                    float4 y0 = *(const float4*)(a2p[i] + k0);
                    float4 y1 = *(const float4*)(a2p[i] + k0 + 4);
                    x0.x += y0.x; x0.y += y0.y; x0.z += y0.z; x0.w += y0.w;
                    x1.x += y1.x; x1.y += y1.y; x1.z += y1.z; x1.w += y1.w;
                }
                af[i] = pkcvt8(x0, x1);
            }
        }
#pragma unroll
        for (int i = 0; i < MT; ++i)
#pragma unroll
            for (int j = 0; j < 4; ++j)
                acc[i][j] = __builtin_amdgcn_mfma_f32_16x16x32_bf16(af[i], bfv[j], acc[i][j], 0, 0, 0);
    };

    if constexpr (KK <= 256) {
#pragma unroll
        for (int k0 = 0; k0 < KK; k0 += 32) step(k0);
    } else {
#pragma unroll 4
        for (int k0 = 0; k0 < KK; k0 += 32) step(k0);
    }

#pragma unroll
    for (int j = 0; j < 4; ++j) {
        const int col = wn + j * 16 + fr;
        const float bb = bias[col];
#pragma unroll
        for (int i = 0; i < MT; ++i) {
            const int rbase = wrow + i * 16 + fq * 4;
#pragma unroll
            for (int r = 0; r < 4; ++r) {
                float v = acc[i][j][r] + bb;
                if (do_relu) v = fmaxf(v, 0.f);
                C[(size_t)(rbase + r) * N + col] = fromF<TC>(v);
            }
        }
    }
}

// ---------------- streaming value GEMM: LDS-staged A via global_load_lds ----------------
// C[M,256] = A[M,256]_f32 @ W[256,256]^T_bf16 + bias -> bf16.
// Block = 128 rows x 128 cols, 4 waves (2m x 2n). A-tile (128x32 f32 = 16 KB)
// staged per K-step with global_load_lds (VGPR-free in-flight buffering),
// XOR-swizzled (byte ^= (row&7)<<4) via pre-swizzled GLOBAL source + swizzled
// ds_read (both-sides rule): kills the 16-way bank conflict of linear [128][32].
__global__ __launch_bounds__(256) void gemm_val(const float* __restrict__ A, const bf16* __restrict__ W,
                                                const float* __restrict__ bias, bf16* __restrict__ C) {
    __shared__ float As[4096];        // 16 KB
    const int tid = threadIdx.x;
    const int lane = tid & 63, wave = tid >> 6;
    const int fr = lane & 15, fq = lane >> 4;
    const int m0 = blockIdx.y * 128;
    const int wm = (wave >> 1) * 64;
    const int wn = blockIdx.x * 128 + (wave & 1) * 64;

    // staging: linear LDS slot s holds global data at column-offset (s&127)^((row&7)<<4)
    int srow[4], soff[4];
#pragma unroll
    for (int g = 0; g < 4; ++g) {
        int s = g * 4096 + tid * 16;
        int r = s >> 7;
        srow[g] = r;
        soff[g] = (s & 127) ^ ((r & 7) << 4);
    }
    // swizzled fragment-read byte offsets
    int rb[4][2];
#pragma unroll
    for (int i = 0; i < 4; ++i) {
        int r2 = wm + i * 16 + fr;
        rb[i][0] = r2 * 128 + ((fq * 32) ^ ((r2 & 7) << 4));
        rb[i][1] = r2 * 128 + ((fq * 32 + 16) ^ ((r2 & 7) << 4));
    }
    const bf16* wp[4];
#pragma unroll
    for (int j = 0; j < 4; ++j) wp[j] = W + (size_t)(wn + j * 16 + fr) * 256 + fq * 8;

    f4v acc[4][4];
#pragma unroll
    for (int i = 0; i < 4; ++i)
#pragma unroll
        for (int j = 0; j < 4; ++j) acc[i][j] = (f4v){0.f, 0.f, 0.f, 0.f};

#pragma unroll
    for (int kk = 0; kk < 8; ++kk) {
        const int k0 = kk * 32;
        __syncthreads();   // prev compute done before overwriting tile
#pragma unroll
        for (int g = 0; g < 4; ++g) {
            const char* gsrc = (const char*)(A + (size_t)(m0 + srow[g]) * 256 + k0) + soff[g];
            gload_lds16(gsrc, (char*)As + g * 4096 + tid * 16);
        }
        __syncthreads();   // compiler drains vmcnt here -> tile ready
        s8v bfv[4];
#pragma unroll
        for (int j = 0; j < 4; ++j) bfv[j] = *(const s8v*)(wp[j] + k0);
        s8v af[4];
#pragma unroll
        for (int i = 0; i < 4; ++i) {
            float4 x0 = *(const float4*)((const char*)As + rb[i][0]);
            float4 x1 = *(const float4*)((const char*)As + rb[i][1]);
            af[i] = pkcvt8(x0, x1);
        }
#pragma unroll
        for (int i = 0; i < 4; ++i)
#pragma unroll
            for (int j = 0; j < 4; ++j)
                acc[i][j] = __builtin_amdgcn_mfma_f32_16x16x32_bf16(af[i], bfv[j], acc[i][j], 0, 0, 0);
    }

#pragma unroll
    for (int j = 0; j < 4; ++j) {
        const int col = wn + j * 16 + fr;
        const float bb = bias[col];
#pragma unroll
        for (int i = 0; i < 4; ++i) {
            const int rbase = m0 + wm + i * 16 + fq * 4;
#pragma unroll
            for (int r = 0; r < 4; ++r) {
                float v = acc[i][j][r] + bb;
                C[(size_t)(rbase + r) * 256 + col] = fromF<bf16>(v);
            }
        }
    }
}

// ---------------- MFMA flash self-attention ----------------
__global__ __launch_bounds__(256) void attn_mfma(const float* __restrict__ q, const float* __restrict__ k,
                                                 const float* __restrict__ v, float* __restrict__ out) {
    const int h = blockIdx.y, n = blockIdx.z;
    const int tid = threadIdx.x, wave = tid >> 6, lane = tid & 63;
    const int fr = lane & 15, fq = lane >> 4;
    __shared__ short Ks[32 * 40];
    __shared__ short Vt[32 * 40];
    __shared__ short Pl[4][16 * 40];
    const int q0 = blockIdx.x * 64 + wave * 16;

    s8v qfrag;
    {
        int qr = q0 + fr; if (qr >= LQ) qr = LQ - 1;
        const float* qp = q + ((size_t)(n * LQ + qr)) * D + h * DH + fq * 8;
        float4 t0 = *(const float4*)qp;
        float4 t1 = *(const float4*)(qp + 4);
        const float sc = 0.17677669529663687f;
        t0.x *= sc; t0.y *= sc; t0.z *= sc; t0.w *= sc;
        t1.x *= sc; t1.y *= sc; t1.z *= sc; t1.w *= sc;
        qfrag = pack8(t0, t1);
    }

    f4v O0 = {0.f, 0.f, 0.f, 0.f}, O1 = {0.f, 0.f, 0.f, 0.f};
    float mrow[4] = {-1e30f, -1e30f, -1e30f, -1e30f};
    float lrow[4] = {0.f, 0.f, 0.f, 0.f};

    for (int kt = 0; kt < LQ; kt += 32) {
        __syncthreads();
        {
            int key = tid >> 3, d4 = (tid & 7) * 4;
            int gk = kt + key; if (gk >= LQ) gk = LQ - 1;
            const float* kp = k + ((size_t)(n * LQ + gk)) * D + h * DH + d4;
            float4 t = *(const float4*)kp;
            short4 pk; pk.x = bfr(t.x); pk.y = bfr(t.y); pk.z = bfr(t.z); pk.w = bfr(t.w);
            *(short4*)&Ks[key * 40 + d4] = pk;
        }
        {
            int d = tid & 31, key0 = (tid >> 5) * 4;
            float vv[4];
#pragma unroll
            for (int i = 0; i < 4; ++i) {
                int gk = kt + key0 + i; if (gk >= LQ) gk = LQ - 1;
                vv[i] = v[((size_t)(n * LQ + gk)) * D + h * DH + d];
            }
            short4 pk; pk.x = bfr(vv[0]); pk.y = bfr(vv[1]); pk.z = bfr(vv[2]); pk.w = bfr(vv[3]);
            *(short4*)&Vt[d * 40 + key0] = pk;
        }
        __syncthreads();

        f4v s0 = {0.f, 0.f, 0.f, 0.f}, s1 = {0.f, 0.f, 0.f, 0.f};
        s8v kf0 = *(s8v*)&Ks[fr * 40 + fq * 8];
        s8v kf1 = *(s8v*)&Ks[(16 + fr) * 40 + fq * 8];
        s0 = __builtin_amdgcn_mfma_f32_16x16x32_bf16(qfrag, kf0, s0, 0, 0, 0);
        s1 = __builtin_amdgcn_mfma_f32_16x16x32_bf16(qfrag, kf1, s1, 0, 0, 0);
        const bool val0 = (kt + fr) < LQ, val1 = (kt + 16 + fr) < LQ;

        float p0[4], p1[4], alpha[4];
#pragma unroll
        for (int r = 0; r < 4; ++r) {
            float a = val0 ? s0[r] : -1e30f;
            float b = val1 ? s1[r] : -1e30f;
            float mx = fmaxf(a, b);
            mx = fmaxf(mx, __shfl_xor(mx, 1, 64));
            mx = fmaxf(mx, __shfl_xor(mx, 2, 64));
            mx = fmaxf(mx, __shfl_xor(mx, 4, 64));
            mx = fmaxf(mx, __shfl_xor(mx, 8, 64));
            float mnew = fmaxf(mrow[r], mx);
            float al = __expf(mrow[r] - mnew);
            float e0 = __expf(a - mnew);
            float e1 = __expf(b - mnew);
            float ps = e0 + e1;
            ps += __shfl_xor(ps, 1, 64);
            ps += __shfl_xor(ps, 2, 64);
            ps += __shfl_xor(ps, 4, 64);
            ps += __shfl_xor(ps, 8, 64);
            lrow[r] = lrow[r] * al + ps;
            mrow[r] = mnew;
            alpha[r] = al;
            p0[r] = e0; p1[r] = e1;
        }

        short* pw = Pl[wave];
#pragma unroll
        for (int r = 0; r < 4; ++r) {
            pw[(fq * 4 + r) * 40 + fr] = bfr(p0[r]);
            pw[(fq * 4 + r) * 40 + 16 + fr] = bfr(p1[r]);
        }
        __builtin_amdgcn_s_waitcnt(0);
        s8v pfrag = *(s8v*)&pw[fr * 40 + fq * 8];
        s8v vf0 = *(s8v*)&Vt[fr * 40 + fq * 8];
        s8v vf1 = *(s8v*)&Vt[(16 + fr) * 40 + fq * 8];
#pragma unroll
        for (int r = 0; r < 4; ++r) { O0[r] *= alpha[r]; O1[r] *= alpha[r]; }
        O0 = __builtin_amdgcn_mfma_f32_16x16x32_bf16(pfrag, vf0, O0, 0, 0, 0);
        O1 = __builtin_amdgcn_mfma_f32_16x16x32_bf16(pfrag, vf1, O1, 0, 0, 0);
    }

#pragma unroll
    for (int r = 0; r < 4; ++r) {
        int qrow = q0 + fq * 4 + r;
        if (qrow < LQ) {
            float inv = 1.0f / lrow[r];
            float* op = out + ((size_t)(n * LQ + qrow)) * D + h * DH;
            op[fr] = O0[r] * inv;
            op[16 + fr] = O1[r] * inv;
        }
    }
}

// ---------------- residual + layernorm ----------------
__global__ __launch_bounds__(256) void ln_res_kernel(const float* __restrict__ base, const float* __restrict__ delta,
                                                     const float* __restrict__ g, const float* __restrict__ b,
                                                     float* __restrict__ out) {
    __shared__ float scratch[8];
    const size_t row = blockIdx.x;
    const int d = threadIdx.x;
    float x = base[row * D + d] + delta[row * D + d];
    float s1 = x, s2 = x * x;
    for (int o = 32; o > 0; o >>= 1) {
        s1 += __shfl_down(s1, o, 64);
        s2 += __shfl_down(s2, o, 64);
    }
    const int w = threadIdx.x >> 6, lane = threadIdx.x & 63;
    if (lane == 0) { scratch[w] = s1; scratch[4 + w] = s2; }
    __syncthreads();
    s1 = scratch[0] + scratch[1] + scratch[2] + scratch[3];
    s2 = scratch[4] + scratch[5] + scratch[6] + scratch[7];
    float mean = s1 * (1.0f / 256.0f);
    float var = s2 * (1.0f / 256.0f) - mean * mean;
    float rstd = rsqrtf(var + 1e-5f);
    float y = (x - mean) * rstd * g[d] + b[d];
    out[row * D + d] = y;
}

// ---------------- softmax over 16 (NL*NP) ----------------
__global__ __launch_bounds__(256) void aw_softmax_kernel(float* __restrict__ aw, int ngrp) {
    int t = blockIdx.x * 256 + threadIdx.x;
    if (t >= ngrp) return;
    float* p = aw + (size_t)t * 16;
    float m = p[0];
#pragma unroll
    for (int i = 1; i < 16; ++i) m = fmaxf(m, p[i]);
    float s = 0.f;
    float e[16];
#pragma unroll
    for (int i = 0; i < 16; ++i) { e[i] = __expf(p[i] - m); s += e[i]; }
    float inv = 1.0f / s;
#pragma unroll
    for (int i = 0; i < 16; ++i) p[i] = e[i] * inv;
}

// ---------------- MS-deformable bilinear sampling ----------------
__global__ __launch_bounds__(256) void deform_kernel(const bf16* __restrict__ value, const float* __restrict__ offs,
                                                     const float* __restrict__ aw, const float* __restrict__ refp,
                                                     float* __restrict__ out) {
    const int h = blockIdx.y, n = blockIdx.z;
    const int tid = threadIdx.x;
    const int wave = tid >> 6, lane = tid & 63;
    const int qi = blockIdx.x * 4 + wave;
    const int c = lane & 15;          // channel pair -> channels 2c, 2c+1
    const int l = lane >> 4;          // level
    const size_t row = (size_t)n * LQ + qi;
    const int W = 128 >> l, H = 128 >> l;
    const int START[4] = {0, 16384, 20480, 21504};
    const float invW = 1.0f / W, invH = 1.0f / H;

    const float rx = refp[(row * NL + l) * 2 + 0];
    const float ry = refp[(row * NL + l) * 2 + 1];
    const bf16* vbase = value + ((size_t)n * LEN_IN + START[l]) * D + h * DH + 2 * c;
    const float* offp = offs + row * D + (h * NL + l) * NP * 2;
    const float* awp = aw + row * 128 + h * 16 + l * 4;

    float acc0 = 0.f, acc1 = 0.f;
#pragma unroll
    for (int p = 0; p < 4; ++p) {
        float ox = offp[p * 2 + 0];
        float oy = offp[p * 2 + 1];
        float wa = awp[p];
        float x = (rx + ox * invW) * W - 0.5f;
        float y = (ry + oy * invH) * H - 0.5f;
        float xf = floorf(x), yf = floorf(y);
        float lx = x - xf, ly = y - yf;
        int x0 = (int)xf, y0 = (int)yf;
        int x1 = x0 + 1, y1 = y0 + 1;
        float vx0 = (x0 >= 0 && x0 < W) ? 1.f : 0.f;
        float vx1 = (x1 >= 0 && x1 < W) ? 1.f : 0.f;
        float vy0 = (y0 >= 0 && y0 < H) ? 1.f : 0.f;
        float vy1 = (y1 >= 0 && y1 < H) ? 1.f : 0.f;
        int x0c = min(max(x0, 0), W - 1), x1c = min(max(x1, 0), W - 1);
        int y0c = min(max(y0, 0), H - 1), y1c = min(max(y1, 0), H - 1);
        float w00 = wa * (1.f - ly) * (1.f - lx) * vy0 * vx0;
        float w01 = wa * (1.f - ly) * lx * vy0 * vx1;
        float w10 = wa * ly * (1.f - lx) * vy1 * vx0;
        float w11 = wa * ly * lx * vy1 * vx1;
        unsigned u00 = *(const unsigned*)(vbase + (size_t)(y0c * W + x0c) * D);
        unsigned u01 = *(const unsigned*)(vbase + (size_t)(y0c * W + x1c) * D);
        unsigned u10 = *(const unsigned*)(vbase + (size_t)(y1c * W + x0c) * D);
        unsigned u11 = *(const unsigned*)(vbase + (size_t)(y1c * W + x1c) * D);
        acc0 += w00 * __uint_as_float(u00 << 16) + w01 * __uint_as_float(u01 << 16)
              + w10 * __uint_as_float(u10 << 16) + w11 * __uint_as_float(u11 << 16);
        acc1 += w00 * __uint_as_float(u00 & 0xffff0000u) + w01 * __uint_as_float(u01 & 0xffff0000u)
              + w10 * __uint_as_float(u10 & 0xffff0000u) + w11 * __uint_as_float(u11 & 0xffff0000u);
    }
    acc0 += __shfl_xor(acc0, 16, 64); acc0 += __shfl_xor(acc0, 32, 64);
    acc1 += __shfl_xor(acc1, 16, 64); acc1 += __shfl_xor(acc1, 32, 64);
    if (l == 0) {
        float2 st = {acc0, acc1};
        *(float2*)(out + row * D + h * DH + 2 * c) = st;
    }
}

// ---------------- host ----------------
extern "C" void kernel_launch(void* const* d_in, const int* in_sizes, int n_in,
                              void* d_out, int out_size, void* d_ws, size_t ws_size,
                              hipStream_t stream) {
    const float* tgt = (const float*)d_in[0];
    const float* qpos = (const float*)d_in[1];
    const float* refp = (const float*)d_in[2];
    const float* src = (const float*)d_in[3];
    const float* sa_in_w = (const float*)d_in[6];
    const float* sa_in_b = (const float*)d_in[7];
    const float* sa_out_w = (const float*)d_in[8];
    const float* sa_out_b = (const float*)d_in[9];
    const float* norm2_g = (const float*)d_in[10];
    const float* norm2_b = (const float*)d_in[11];
    const float* off_w = (const float*)d_in[12];
    const float* off_b = (const float*)d_in[13];
    const float* aw_w = (const float*)d_in[14];
    const float* aw_b = (const float*)d_in[15];
    const float* val_w = (const float*)d_in[16];
    const float* val_b = (const float*)d_in[17];
    const float* outp_w = (const float*)d_in[18];
    const float* outp_b = (const float*)d_in[19];
    const float* norm1_g = (const float*)d_in[20];
    const float* norm1_b = (const float*)d_in[21];
    const float* ffn_w1 = (const float*)d_in[22];
    const float* ffn_b1 = (const float*)d_in[23];
    const float* ffn_w2 = (const float*)d_in[24];
    const float* ffn_b2 = (const float*)d_in[25];
    const float* norm3_g = (const float*)d_in[26];
    const float* norm3_b = (const float*)d_in[27];
    float* outp = (float*)d_out;

    const size_t NTOK = (size_t)NB * LQ;          // 8000
    const size_t NE = NTOK * D;                   // 2,048,000
    float* w = (float*)d_ws;
    size_t off = 0;
    auto alloc = [&](size_t n) { float* p = w + off; off += n; return p; };
    float* bufA = alloc(NE);          // att -> dout
    float* bufB = alloc(NE);          // q -> sap -> ca
    float* bufC = alloc(NE);          // k -> ff
    float* bufD = alloc(NE);          // v -> offs
    float* tgt2 = alloc(NE);
    float* tgt3 = alloc(NE);
    float* awb = alloc(NTOK * 128);
    bf16* mid = (bf16*)alloc(NTOK * DFFN / 2);            // FFN mid, bf16
    bf16* value = (bf16*)alloc((size_t)NB * LEN_IN * D / 2); // (NB*LEN_IN, D) bf16
    bf16* wb = (bf16*)alloc(507904);                      // packed bf16 weights (1,015,808 elems)

    // packed weight layout (element offsets)
    const bf16* wq    = wb;            // sa_in rows 0..255
    const bf16* wk    = wb + 65536;    // sa_in rows 256..511
    const bf16* wv    = wb + 131072;   // sa_in rows 512..767
    const bf16* wo    = wb + 196608;   // sa_out
    const bf16* woff  = wb + 262144;
    const bf16* waw   = wb + 327680;
    const bf16* wval  = wb + 360448;
    const bf16* woutp = wb + 425984;
    const bf16* wf1   = wb + 491520;
    const bf16* wf2   = wb + 753664;

    const int M8K = (int)NTOK;        // 8000
    dim3 g8(2, M8K / 64);             // N=256 GEMMs, 64-row tiles -> 250 blocks
    dim3 g8aw(1, M8K / 64);           // N=128
    dim3 g8f1(DFFN / 128, M8K / 64);  // N=1024 -> 1000 blocks
    dim3 gVal(2, (NB * LEN_IN) / 128);// 174080 rows, 128-row tiles -> 2720 blocks

    pack_weights<<<992, 256, 0, stream>>>(sa_in_w, sa_out_w, off_w, aw_w, val_w, outp_w, ffn_w1, ffn_w2, wb);

    // ---- self attention ----
    gemm_direct<float, float, 2, true, 256><<<g8, 256, 0, stream>>>(tgt, qpos, wq, sa_in_b, bufB, D, 0);        // Q
    gemm_direct<float, float, 2, true, 256><<<g8, 256, 0, stream>>>(tgt, qpos, wk, sa_in_b + 256, bufC, D, 0);  // K
    gemm_direct<float, float, 2, false, 256><<<g8, 256, 0, stream>>>(tgt, nullptr, wv, sa_in_b + 512, bufD, D, 0); // V
    attn_mfma<<<dim3((LQ + 63) / 64, NH, NB), 256, 0, stream>>>(bufB, bufC, bufD, bufA);                        // att
    gemm_direct<float, float, 2, false, 256><<<g8, 256, 0, stream>>>(bufA, nullptr, wo, sa_out_b, bufB, D, 0);  // sap
    ln_res_kernel<<<NTOK, 256, 0, stream>>>(tgt, bufB, norm2_g, norm2_b, tgt2);

    // ---- deformable attention ----
    gemm_val<<<gVal, 256, 0, stream>>>(src, wval, val_b, value);                                                // value
    gemm_direct<float, float, 2, true, 256><<<g8, 256, 0, stream>>>(tgt2, qpos, woff, off_b, bufD, D, 0);       // offsets
    gemm_direct<float, float, 2, true, 256><<<g8aw, 256, 0, stream>>>(tgt2, qpos, waw, aw_b, awb, 128, 0);      // aw
    aw_softmax_kernel<<<(int)(NTOK * NH + 255) / 256, 256, 0, stream>>>(awb, (int)(NTOK * NH));
    deform_kernel<<<dim3(LQ / 4, NH, NB), 256, 0, stream>>>(value, bufD, awb, refp, bufA);                      // dout
    gemm_direct<float, float, 2, false, 256><<<g8, 256, 0, stream>>>(bufA, nullptr, woutp, outp_b, bufB, D, 0); // ca
    ln_res_kernel<<<NTOK, 256, 0, stream>>>(tgt2, bufB, norm1_g, norm1_b, tgt3);

    // ---- FFN ----
    gemm_direct<float, bf16, 2, false, 256><<<g8f1, 256, 0, stream>>>(tgt3, nullptr, wf1, ffn_b1, mid, DFFN, 1);
    gemm_direct<bf16, float, 2, false, 1024><<<g8, 256, 0, stream>>>(mid, nullptr, wf2, ffn_b2, bufC, D, 0);    // ff
    ln_res_kernel<<<NTOK, 256, 0, stream>>>(tgt3, bufC, norm3_g, norm3_b, outp);
}